// Round 6
// baseline (919.896 us; speedup 1.0000x reference)
//
#include <hip/hip_runtime.h>
#include <stdint.h>

#define H_DIM    512
#define NUM_BASES 128

typedef __attribute__((ext_vector_type(4))) float f32x4;
typedef __attribute__((ext_vector_type(8))) short bf16x8;

__device__ __forceinline__ short f32_bf16(float f) {
  union { float f; unsigned u; } x; x.f = f;
  unsigned r = x.u + 0x7FFF + ((x.u >> 16) & 1);   // RNE
  return (short)(r >> 16);
}
__device__ __forceinline__ float bf16_f32(short s) {
  union { unsigned u; float f; } x; x.u = ((unsigned)(unsigned short)s) << 16;
  return x.f;
}

__device__ __forceinline__ void gload_lds16(const void* g, void* l) {
  __builtin_amdgcn_global_load_lds(
      (const __attribute__((address_space(1))) uint32_t*)g,
      (__attribute__((address_space(3))) uint32_t*)l, 16, 0, 0);
}

// ---------------------------------------------------------------------------
// A-prep: emb [M][512] fp32 -> Ah/Al [Mpad][512] bf16 (hi/lo split, pad=0)
// ---------------------------------------------------------------------------
__global__ __launch_bounds__(256) void aprep(const float* __restrict__ A,
                                             short* __restrict__ Ah,
                                             short* __restrict__ Al,
                                             int M, int Mpad) {
  const int row = blockIdx.x * 2 + (threadIdx.x >> 7);
  const int col = (threadIdx.x & 127) * 4;
  if (row >= Mpad) return;
  float4 v = make_float4(0.f, 0.f, 0.f, 0.f);
  if (row < M) v = *(const float4*)(A + (size_t)row * H_DIM + col);
  short h0 = f32_bf16(v.x), h1 = f32_bf16(v.y), h2 = f32_bf16(v.z), h3 = f32_bf16(v.w);
  short e0 = f32_bf16(v.x - bf16_f32(h0)), e1 = f32_bf16(v.y - bf16_f32(h1));
  short e2 = f32_bf16(v.z - bf16_f32(h2)), e3 = f32_bf16(v.w - bf16_f32(h3));
  *(short4*)(Ah + (size_t)row * H_DIM + col) = make_short4(h0, h1, h2, h3);
  *(short4*)(Al + (size_t)row * H_DIM + col) = make_short4(e0, e1, e2, e3);
}

// ---------------------------------------------------------------------------
// B-prep: loop_weight [K=512][N=512] fp32 -> Bt_hi/Bt_lo [N][K] bf16
// ---------------------------------------------------------------------------
__global__ __launch_bounds__(256) void bprep(const float* __restrict__ B,
                                             short* __restrict__ Bt_hi,
                                             short* __restrict__ Bt_lo) {
  __shared__ float T[32][33];
  const int k0 = blockIdx.x * 32, n0 = blockIdx.y * 32;
  const int tid = threadIdx.x;
#pragma unroll
  for (int q = 0; q < 4; ++q) {
    int idx = tid + q * 256;
    int kk = idx >> 5, nn = idx & 31;
    T[kk][nn] = B[(k0 + kk) * H_DIM + n0 + nn];
  }
  __syncthreads();
#pragma unroll
  for (int q = 0; q < 4; ++q) {
    int idx = tid + q * 256;
    int nn = idx >> 5, kk = idx & 31;
    float v = T[kk][nn];
    short hi = f32_bf16(v);
    short lo = f32_bf16(v - bf16_f32(hi));
    Bt_hi[(size_t)(n0 + nn) * H_DIM + k0 + kk] = hi;
    Bt_lo[(size_t)(n0 + nn) * H_DIM + k0 + kk] = lo;
  }
}

// ---------------------------------------------------------------------------
// GEMM v3 (m97 structure): all-bf16 inputs, global_load_lds(16B) staging with
// pre-swizzled global source (granule ^= row&7), linear LDS dest, swizzled
// ds_read_b128. 128x128 tile, BK=64, 4 waves, 3-term split-bf16 MFMA.
// 1D grid with bijective XCD chunking: the 4 n-tiles of an m-row run
// back-to-back on one XCD -> A panel L2-resident.
// ---------------------------------------------------------------------------
__global__ __launch_bounds__(256, 2) void mfma_gemm3(
    const short* __restrict__ Ah,   // [Mpad][512] bf16
    const short* __restrict__ Al,
    const short* __restrict__ Bh,   // [512(n)][512(k)] bf16
    const short* __restrict__ Bl,
    const float* __restrict__ bias,
    float* __restrict__ C, int M) {
  __shared__ short sAh[8192], sAl[8192], sBh[8192], sBl[8192];  // 4 x 16KB

  const int tid = threadIdx.x;
  const int lane = tid & 63;
  const int wv = tid >> 6;

  // bijective XCD swizzle (m204): lin enumerates (m-row, n-tile) with n inner
  const int nwg = gridDim.x;
  const int q = nwg >> 3, rmd = nwg & 7;
  const int xcd = blockIdx.x & 7, j = blockIdx.x >> 3;
  const int lin = (xcd < rmd ? xcd * (q + 1) : rmd * (q + 1) + (xcd - rmd) * q) + j;
  const int row0 = (lin >> 2) * 128;
  const int col0 = (lin & 3) * 128;

  const int wm = (wv >> 1) * 64;
  const int wn = (wv & 1) * 64;
  const int l15 = lane & 15;
  const int l4 = lane >> 4;

  // staging geometry: per array per K-step, wave wv stages rows 32*wv..32*wv+31
  // in 4 issues of 8 rows (64 lanes x 16B = 1KB). lane -> (rowoff = lane>>3,
  // granule gd = lane&7); global granule = gd ^ (row&7)  [inverse of read swz]
  const int st_rowoff = lane >> 3;
  const int st_gd = lane & 7;

  f32x4 acc[4][4] = {};

  for (int k0 = 0; k0 < H_DIM; k0 += 64) {
#pragma unroll
    for (int qq = 0; qq < 4; ++qq) {
      const int brow = wv * 32 + qq * 8;          // tile row base for this issue
      const int trow = brow + st_rowoff;          // tile row this lane reads
      const int gsh = (st_gd ^ (trow & 7)) * 8;   // swizzled source col (shorts)
      const size_t aoff = (size_t)(row0 + trow) * H_DIM + k0 + gsh;
      const size_t boff = (size_t)(col0 + trow) * H_DIM + k0 + gsh;
      const int ldso = brow * 64;                 // linear LDS dest (shorts)
      gload_lds16(Ah + aoff, &sAh[ldso]);
      gload_lds16(Al + aoff, &sAl[ldso]);
      gload_lds16(Bh + boff, &sBh[ldso]);
      gload_lds16(Bl + boff, &sBl[ldso]);
    }
    __syncthreads();   // drains vmcnt (incl. global_load_lds) + lgkm

#pragma unroll
    for (int kk = 0; kk < 2; ++kk) {
      bf16x8 ah[4], al[4], bh[4], bl[4];
      const int gc = kk * 4 + l4;                 // granule col of fragment
#pragma unroll
      for (int i = 0; i < 4; ++i) {
        const int ra = wm + 16 * i + l15;
        const int sia = ra * 64 + (gc ^ (ra & 7)) * 8;
        ah[i] = *(const bf16x8*)&sAh[sia];
        al[i] = *(const bf16x8*)&sAl[sia];
        const int rb = wn + 16 * i + l15;
        const int sib = rb * 64 + (gc ^ (rb & 7)) * 8;
        bh[i] = *(const bf16x8*)&sBh[sib];
        bl[i] = *(const bf16x8*)&sBl[sib];
      }
#pragma unroll
      for (int i = 0; i < 4; ++i)
#pragma unroll
        for (int jj = 0; jj < 4; ++jj) {
          acc[i][jj] = __builtin_amdgcn_mfma_f32_16x16x32_bf16(ah[i], bh[jj], acc[i][jj], 0, 0, 0);
          acc[i][jj] = __builtin_amdgcn_mfma_f32_16x16x32_bf16(ah[i], bl[jj], acc[i][jj], 0, 0, 0);
          acc[i][jj] = __builtin_amdgcn_mfma_f32_16x16x32_bf16(al[i], bh[jj], acc[i][jj], 0, 0, 0);
        }
    }
    __syncthreads();
  }

  float bv[4];
#pragma unroll
  for (int jj = 0; jj < 4; ++jj) bv[jj] = bias[col0 + wn + 16 * jj + l15];
#pragma unroll
  for (int i = 0; i < 4; ++i) {
#pragma unroll
    for (int r = 0; r < 4; ++r) {
      const int grow = row0 + wm + 16 * i + l4 * 4 + r;
      if (grow < M) {
#pragma unroll
        for (int jj = 0; jj < 4; ++jj)
          C[(size_t)grow * H_DIM + col0 + wn + 16 * jj + l15] = acc[i][jj][r] + bv[jj];
      }
    }
  }
}

// ---------------------------------------------------------------------------
// Edge path: per-dst linked list, gather-side aggregation, 4-way branchless
// chain unroll (invalid links clamp to e0 -> same-line L1 hits, norm=0).
// ---------------------------------------------------------------------------
__global__ void init_head(int* head, int N) {
  int i = blockIdx.x * 256 + threadIdx.x;
  if (i < N) head[i] = -1;
}

__global__ void fill_ll(const int* __restrict__ dst, int* head, int* next, int E) {
  int e = blockIdx.x * 256 + threadIdx.x;
  if (e < E) next[e] = atomicExch(&head[dst[e]], e);
}

__device__ __forceinline__ void edge_fma(const float* __restrict__ emb,
                                         const float* __restrict__ W,
                                         int s, int r, int b, float nrm,
                                         float4& a) {
  const float4 h = *(const float4*)(emb + (size_t)s * H_DIM + b * 4);
  const float4* w = (const float4*)(W + ((size_t)r * NUM_BASES + b) * 16);
  const float4 w0 = w[0], w1 = w[1], w2 = w[2], w3 = w[3];
  a.x += nrm * (h.x * w0.x + h.y * w1.x + h.z * w2.x + h.w * w3.x);
  a.y += nrm * (h.x * w0.y + h.y * w1.y + h.z * w2.y + h.w * w3.y);
  a.z += nrm * (h.x * w0.z + h.y * w1.z + h.z * w2.z + h.w * w3.z);
  a.w += nrm * (h.x * w0.w + h.y * w1.w + h.z * w2.w + h.w * w3.w);
}

__global__ __launch_bounds__(256) void edge_agg(
    const int* __restrict__ head, const int* __restrict__ next,
    const int* __restrict__ src, const int* __restrict__ et,
    const float* __restrict__ norm, const float* __restrict__ emb,
    const float* __restrict__ W, float* __restrict__ out, int N) {
  const int node = blockIdx.x * 2 + (threadIdx.x >> 7);
  if (node >= N) return;
  const int b = threadIdx.x & 127;
  int e = head[node];
  if (e < 0) return;
  float4 a = make_float4(0.f, 0.f, 0.f, 0.f);
  while (e >= 0) {
    const int e0 = e;
    const int e1 = next[e0];
    const bool v1 = e1 >= 0; const int f1 = v1 ? e1 : e0;
    const int e2 = v1 ? next[e1] : -1;
    const bool v2 = e2 >= 0; const int f2 = v2 ? e2 : e0;
    const int e3 = v2 ? next[e2] : -1;
    const bool v3 = e3 >= 0; const int f3 = v3 ? e3 : e0;
    e = v3 ? next[e3] : -1;

    const float n0 = norm[e0];
    const float n1 = v1 ? norm[f1] : 0.f;
    const float n2 = v2 ? norm[f2] : 0.f;
    const float n3 = v3 ? norm[f3] : 0.f;
    const int s0 = src[e0], s1 = src[f1], s2 = src[f2], s3 = src[f3];
    const int r0 = et[e0], r1 = et[f1], r2 = et[f2], r3 = et[f3];

    edge_fma(emb, W, s0, r0, b, n0, a);
    edge_fma(emb, W, s1, r1, b, n1, a);
    edge_fma(emb, W, s2, r2, b, n2, a);
    edge_fma(emb, W, s3, r3, b, n3, a);
  }
  float4* op = (float4*)(out + (size_t)node * H_DIM + b * 4);
  float4 cur = *op;
  cur.x += a.x; cur.y += a.y; cur.z += a.z; cur.w += a.w;
  *op = cur;
}

// ---------------------------------------------------------------------------
// Tier-1 fallback (R1 GEMM, conversion inside kernel; used if ws < ~208MB)
// ---------------------------------------------------------------------------
__global__ __launch_bounds__(256) void mfma_gemm(
    const float* __restrict__ A, const short* __restrict__ Bt_hi,
    const short* __restrict__ Bt_lo, const float* __restrict__ bias,
    float* __restrict__ C, int M) {
  __shared__ short sAh[8192], sAl[8192], sBh[8192], sBl[8192];
  const int tid = threadIdx.x;
  const int lane = tid & 63;
  const int wave = tid >> 6;
  const int col0 = blockIdx.x * 128;
  const int row0 = blockIdx.y * 128;
  const int wm = (wave >> 1) * 64;
  const int wn = (wave & 1) * 64;
  const int l15 = lane & 15;
  const int l4 = lane >> 4;
  f32x4 acc[4][4] = {};
  for (int k0 = 0; k0 < H_DIM; k0 += 64) {
#pragma unroll
    for (int q = 0; q < 8; ++q) {
      const int f = tid + q * 256;
      const int row = f >> 4;
      const int col = (f & 15) * 4;
      const int si = ((row << 6) + col) ^ ((row & 7) << 3);
      float4 v = make_float4(0.f, 0.f, 0.f, 0.f);
      const int grow = row0 + row;
      if (grow < M) v = *(const float4*)(A + (size_t)grow * H_DIM + k0 + col);
      short h0 = f32_bf16(v.x), h1 = f32_bf16(v.y), h2 = f32_bf16(v.z), h3 = f32_bf16(v.w);
      short e0 = f32_bf16(v.x - bf16_f32(h0)), e1 = f32_bf16(v.y - bf16_f32(h1));
      short e2 = f32_bf16(v.z - bf16_f32(h2)), e3 = f32_bf16(v.w - bf16_f32(h3));
      *(short4*)&sAh[si] = make_short4(h0, h1, h2, h3);
      *(short4*)&sAl[si] = make_short4(e0, e1, e2, e3);
      *(short4*)&sBh[si] = *(const short4*)(Bt_hi + (size_t)(col0 + row) * H_DIM + k0 + col);
      *(short4*)&sBl[si] = *(const short4*)(Bt_lo + (size_t)(col0 + row) * H_DIM + k0 + col);
    }
    __syncthreads();
#pragma unroll
    for (int kk = 0; kk < 2; ++kk) {
      bf16x8 ah[4], al[4], bh[4], bl[4];
      const int cbase = kk * 32 + l4 * 8;
#pragma unroll
      for (int i = 0; i < 4; ++i) {
        const int ra = wm + 16 * i + l15;
        const int sia = ((ra << 6) + cbase) ^ ((ra & 7) << 3);
        ah[i] = *(const bf16x8*)&sAh[sia];
        al[i] = *(const bf16x8*)&sAl[sia];
        const int rb = wn + 16 * i + l15;
        const int sib = ((rb << 6) + cbase) ^ ((rb & 7) << 3);
        bh[i] = *(const bf16x8*)&sBh[sib];
        bl[i] = *(const bf16x8*)&sBl[sib];
      }
#pragma unroll
      for (int i = 0; i < 4; ++i)
#pragma unroll
        for (int jj = 0; jj < 4; ++jj) {
          acc[i][jj] = __builtin_amdgcn_mfma_f32_16x16x32_bf16(ah[i], bh[jj], acc[i][jj], 0, 0, 0);
          acc[i][jj] = __builtin_amdgcn_mfma_f32_16x16x32_bf16(ah[i], bl[jj], acc[i][jj], 0, 0, 0);
          acc[i][jj] = __builtin_amdgcn_mfma_f32_16x16x32_bf16(al[i], bh[jj], acc[i][jj], 0, 0, 0);
        }
    }
    __syncthreads();
  }
  float bv[4];
#pragma unroll
  for (int jj = 0; jj < 4; ++jj) bv[jj] = bias[col0 + wn + 16 * jj + l15];
#pragma unroll
  for (int i = 0; i < 4; ++i) {
#pragma unroll
    for (int r = 0; r < 4; ++r) {
      const int grow = row0 + wm + 16 * i + l4 * 4 + r;
      if (grow < M) {
#pragma unroll
        for (int jj = 0; jj < 4; ++jj)
          C[(size_t)grow * H_DIM + col0 + wn + 16 * jj + l15] = acc[i][jj][r] + bv[jj];
      }
    }
  }
}

// Tier-2 fallback (R0 kernels)
__global__ __launch_bounds__(256) void selfloop_gemm(
    const float* __restrict__ A, const float* __restrict__ B,
    const float* __restrict__ bias, float* __restrict__ C, int M) {
  __shared__ float As[32][65];
  __shared__ float Bs[32][64];
  const int tid = threadIdx.x;
  const int row0 = blockIdx.x * 64;
  const int col0 = blockIdx.y * 64;
  const int tx = tid & 15;
  const int ty = tid >> 4;
  float acc[4][4] = {};
  for (int k0 = 0; k0 < H_DIM; k0 += 32) {
#pragma unroll
    for (int q = 0; q < 2; ++q) {
      const int f = tid + q * 256;
      const int kk = (f & 7) * 4;
      const int r = f >> 3;
      const int grow = row0 + r;
      float4 v = make_float4(0.f, 0.f, 0.f, 0.f);
      if (grow < M) v = *(const float4*)(A + (size_t)grow * H_DIM + k0 + kk);
      As[kk + 0][r] = v.x; As[kk + 1][r] = v.y; As[kk + 2][r] = v.z; As[kk + 3][r] = v.w;
    }
#pragma unroll
    for (int q = 0; q < 2; ++q) {
      const int f = tid + q * 256;
      const int nn = (f & 15) * 4;
      const int kk = f >> 4;
      *(float4*)(&Bs[kk][nn]) = *(const float4*)(B + (size_t)(k0 + kk) * H_DIM + col0 + nn);
    }
    __syncthreads();
#pragma unroll
    for (int kk = 0; kk < 32; ++kk) {
      float a[4];
#pragma unroll
      for (int i = 0; i < 4; ++i) a[i] = As[kk][ty * 4 + i];
      const float4 bvv = *(const float4*)(&Bs[kk][tx * 4]);
      const float bb[4] = {bvv.x, bvv.y, bvv.z, bvv.w};
#pragma unroll
      for (int i = 0; i < 4; ++i)
#pragma unroll
        for (int jj = 0; jj < 4; ++jj) acc[i][jj] = fmaf(a[i], bb[jj], acc[i][jj]);
    }
    __syncthreads();
  }
  const float4 bz = *(const float4*)(bias + col0 + tx * 4);
#pragma unroll
  for (int i = 0; i < 4; ++i) {
    const int grow = row0 + ty * 4 + i;
    if (grow < M) {
      float4 o;
      o.x = acc[i][0] + bz.x; o.y = acc[i][1] + bz.y;
      o.z = acc[i][2] + bz.z; o.w = acc[i][3] + bz.w;
      *(float4*)(C + (size_t)grow * H_DIM + col0 + tx * 4) = o;
    }
  }
}

__global__ __launch_bounds__(256) void edge_message(
    const int* __restrict__ src, const int* __restrict__ dst,
    const int* __restrict__ etypes, const float* __restrict__ norm,
    const float* __restrict__ emb, const float* __restrict__ W,
    float* __restrict__ out, int nE) {
  const int b = threadIdx.x & 127;
  const int e = blockIdx.x * 2 + (threadIdx.x >> 7);
  if (e >= nE) return;
  const int s = src[e];
  const int d = dst[e];
  const int r = etypes[e];
  const float nrm = norm[e];
  const float4 h = *(const float4*)(emb + (size_t)s * H_DIM + b * 4);
  const float4* w = (const float4*)(W + ((size_t)r * NUM_BASES + b) * 16);
  const float4 w0 = w[0], w1 = w[1], w2 = w[2], w3 = w[3];
  float* op = out + (size_t)d * H_DIM + b * 4;
  atomicAdd(op + 0, (h.x * w0.x + h.y * w1.x + h.z * w2.x + h.w * w3.x) * nrm);
  atomicAdd(op + 1, (h.x * w0.y + h.y * w1.y + h.z * w2.y + h.w * w3.y) * nrm);
  atomicAdd(op + 2, (h.x * w0.z + h.y * w1.z + h.z * w2.z + h.w * w3.z) * nrm);
  atomicAdd(op + 3, (h.x * w0.w + h.y * w1.w + h.z * w2.w + h.w * w3.w) * nrm);
}

// ---------------------------------------------------------------------------
extern "C" void kernel_launch(void* const* d_in, const int* in_sizes, int n_in,
                              void* d_out, int out_size, void* d_ws, size_t ws_size,
                              hipStream_t stream) {
  const int* src = (const int*)d_in[1];
  const int* dst = (const int*)d_in[2];
  const int* etypes = (const int*)d_in[3];
  const float* norm = (const float*)d_in[4];
  const float* emb = (const float*)d_in[5];
  const float* weight = (const float*)d_in[6];
  const float* loop_weight = (const float*)d_in[7];
  const float* bias = (const float*)d_in[8];
  float* out = (float*)d_out;

  const int nE = in_sizes[1];
  const int M = in_sizes[5] / H_DIM;
  const int Mpad = ((M + 127) / 128) * 128;

  // ws layout tier0: head[M] | next[nE] | Ah | Al | Bh | Bl
  const size_t ll_bytes = ((size_t)(M + nE) * 4 + 255) & ~(size_t)255;
  const size_t a_bytes = (size_t)Mpad * H_DIM * 2;
  const size_t b_bytes = (size_t)H_DIM * H_DIM * 2;
  const size_t ws_t0 = ll_bytes + 2 * a_bytes + 2 * b_bytes;
  const size_t ws_t1 = ll_bytes + 2 * b_bytes;

  if (ws_size >= ws_t0) {
    int* head = (int*)d_ws;
    int* next = head + M;
    short* Ah = (short*)((char*)d_ws + ll_bytes);
    short* Al = Ah + (size_t)Mpad * H_DIM;
    short* Bh = Al + (size_t)Mpad * H_DIM;
    short* Bl = Bh + (size_t)H_DIM * H_DIM;

    aprep<<<Mpad / 2, 256, 0, stream>>>(emb, Ah, Al, M, Mpad);
    dim3 bg(H_DIM / 32, H_DIM / 32);
    bprep<<<bg, 256, 0, stream>>>(loop_weight, Bh, Bl);
    init_head<<<(M + 255) / 256, 256, 0, stream>>>(head, M);
    fill_ll<<<(nE + 255) / 256, 256, 0, stream>>>(dst, head, next, nE);

    const int nwg = (Mpad / 128) * 4;
    mfma_gemm3<<<nwg, 256, 0, stream>>>(Ah, Al, Bh, Bl, bias, out, M);

    edge_agg<<<(M + 1) / 2, 256, 0, stream>>>(head, next, src, etypes, norm,
                                              emb, weight, out, M);
  } else if (ws_size >= ws_t1) {
    int* head = (int*)d_ws;
    int* next = head + M;
    short* Bh = (short*)((char*)d_ws + ll_bytes);
    short* Bl = Bh + (size_t)H_DIM * H_DIM;

    dim3 bg(H_DIM / 32, H_DIM / 32);
    bprep<<<bg, 256, 0, stream>>>(loop_weight, Bh, Bl);
    init_head<<<(M + 255) / 256, 256, 0, stream>>>(head, M);
    fill_ll<<<(nE + 255) / 256, 256, 0, stream>>>(dst, head, next, nE);

    dim3 gg(H_DIM / 128, (Mpad / 128));
    mfma_gemm<<<gg, 256, 0, stream>>>(emb, Bh, Bl, bias, out, M);

    edge_agg<<<(M + 1) / 2, 256, 0, stream>>>(head, next, src, etypes, norm,
                                              emb, weight, out, M);
  } else {
    dim3 ggrid((M + 63) / 64, H_DIM / 64);
    selfloop_gemm<<<ggrid, 256, 0, stream>>>(emb, loop_weight, bias, out, M);
    edge_message<<<(nE + 1) / 2, 256, 0, stream>>>(src, dst, etypes, norm, emb,
                                                   weight, out, nE);
  }
}